// Round 16
// baseline (63.751 us; speedup 1.0000x reference)
//
#include <hip/hip_runtime.h>
#include <hip/hip_bf16.h>
#include <cstdint>
#include <cstddef>

// Problem constants (B=2, N=2048, C=512, H=8, D=64, EPEG_K=5)
#define NB 2
#define NN 2048
#define NC 512
#define NH 8
#define ND 64
#define NF3 1536
#define ATT_SCALE 0.125f
#define LOG2E 1.44269504088896340736f

typedef __bf16 bf16x8 __attribute__((ext_vector_type(8)));
typedef unsigned short u16x8 __attribute__((ext_vector_type(8)));
typedef float f32x4 __attribute__((ext_vector_type(4)));

// round-to-nearest-even f32 -> bf16 (inputs are finite)
__device__ __forceinline__ unsigned short f2bf(float f){
  unsigned int u = __builtin_bit_cast(unsigned int, f);
  u += 0x7fffu + ((u >> 16) & 1u);
  return (unsigned short)(u >> 16);
}
__device__ __forceinline__ float bf2f(unsigned short s){
  unsigned int u = ((unsigned int)s) << 16;
  return __builtin_bit_cast(float, u);
}
// pack two f32 -> one u32 of 2 bf16 (RNE)
__device__ __forceinline__ unsigned int pkbf2(float lo, float hi){
  return (unsigned int)f2bf(lo) | ((unsigned int)f2bf(hi) << 16);
}
// hardware packed convert: dst = {bf16(lo), bf16(hi)} (RNE), 1 instruction
__device__ __forceinline__ unsigned int cvtpk_bf2(float lo, float hi){
  unsigned int r;
  asm("v_cvt_pk_bf16_f32 %0, %1, %2" : "=v"(r) : "v"(lo), "v"(hi));
  return r;
}
// hardware exp2: D = 2^S0 (v_exp_f32 IS the 2^x op)
__device__ __forceinline__ float exp2_hw(float x){
  float r;
  asm("v_exp_f32 %0, %1" : "=v"(r) : "v"(x));
  return r;
}

__device__ __forceinline__ bf16x8 ldfrag(const void* p){
  return __builtin_bit_cast(bf16x8, *(const u16x8*)p);
}

// async global->LDS, 16B per lane; LDS dest = wave-uniform base + lane*16,
// global source is PER-LANE (swizzled LDS layout = pre-swizzled source).
__device__ __forceinline__ void gload16(const void* g, void* l){
  __builtin_amdgcn_global_load_lds((const __attribute__((address_space(1))) unsigned int*)g,
                                   (__attribute__((address_space(3))) unsigned int*)l, 16, 0, 0);
}

// converts the two weight matrices to bf16 (x is converted inline in GEMM1)
__global__ void f2bf2_kernel(const float* __restrict__ a, unsigned short* __restrict__ oa, int na,
                             const float* __restrict__ b, unsigned short* __restrict__ ob, int nb){
  int i = (blockIdx.x * 256 + threadIdx.x) * 4;
  const float* src; unsigned short* dst; int off;
  if (i < na)            { src = a; dst = oa; off = i; }
  else if (i < na + nb)  { src = b; dst = ob; off = i - na; }
  else return;
  float4 v = *(const float4*)(src + off);
  *(uint2*)(dst + off) = make_uint2(pkbf2(v.x, v.y), pkbf2(v.z, v.w));
}

// C = A[M,K] @ B[N,K]^T + bias.  B bf16 row-major; A bf16 (AF32=0, gload_lds)
// or f32 (AF32=1, reg-staged + cvt_pk -> same RNE bf16, bit-identical).
// BM x BN block tile, 4 waves, wave tile (BM/2)x(BN/2).
// EPI==0: write fp32 to outF[M,Nn]. EPI==1: scatter bf16 Q/K/V (V transposed).
template<int EPI, int BM, int BN, int AF32>
__global__ __launch_bounds__(256, (BM == 64 ? 3 : 2)) void gemm_bt(
    const void* __restrict__ Araw, const unsigned short* __restrict__ Bm,
    const float* __restrict__ bias, float* __restrict__ outF,
    unsigned short* __restrict__ Qb, unsigned short* __restrict__ Kb,
    unsigned short* __restrict__ Vb, int M, int Nn, int K)
{
  __shared__ unsigned short As[BM*32];    // [BM][32] bf16, 64B rows
  __shared__ unsigned short Bs[BN*32];
  const int tid = threadIdx.x;
  const int w = tid >> 6, l = tid & 63;
  const int bm = blockIdx.x, bn = blockIdx.y;
  const int wr = (w >> 1) * (BM/2), wc = (w & 1) * (BN/2);
  const int l4 = l >> 4, l15 = l & 15;
  constexpr int MF = BM / 32;             // m-frags per wave
  constexpr int NF = BN / 32;             // n-frags per wave

  f32x4 acc[MF][NF];
  #pragma unroll
  for (int i=0;i<MF;i++)
    #pragma unroll
    for (int j=0;j<NF;j++)
      #pragma unroll
      for (int r=0;r<4;r++) acc[i][j][r] = 0.f;

  const int KT = K >> 5;
  for (int kt = 0; kt < KT; ++kt){
    const int kc = kt << 5;
    if constexpr (AF32){
      // A is f32: reg-stage 8 elems/lane, convert (RNE), one ds_write_b128.
      const float* Af = (const float*)Araw;
      #pragma unroll
      for (int c = 0; c < BM/64; ++c){
        const int ar = w*(BM/4) + c*16 + (l>>2);
        const int ac = (l&3)*8;
        const float* ap = Af + (size_t)(bm*BM + ar)*K + kc + ac;
        float4 v0 = *(const float4*)ap;
        float4 v1 = *(const float4*)(ap + 4);
        *(uint4*)&As[ar*32 + ac] = make_uint4(cvtpk_bf2(v0.x, v0.y), cvtpk_bf2(v0.z, v0.w),
                                              cvtpk_bf2(v1.x, v1.y), cvtpk_bf2(v1.z, v1.w));
      }
    } else {
      const unsigned short* A = (const unsigned short*)Araw;
      #pragma unroll
      for (int c = 0; c < BM/64; ++c){    // A: BM rows in 16-row chunks
        const int rbase = w*(BM/4) + c*16;
        gload16(A + (size_t)(bm*BM + rbase + (l>>2))*K + kc + (l&3)*8, &As[rbase*32]);
      }
    }
    #pragma unroll
    for (int c = 0; c < BN/64; ++c){      // B: BN rows in 16-row chunks
      const int rbase = w*(BN/4) + c*16;
      gload16(Bm + (size_t)(bn*BN + rbase + (l>>2))*K + kc + (l&3)*8, &Bs[rbase*32]);
    }
    __syncthreads();
    bf16x8 af[MF], bfr[NF];
    #pragma unroll
    for (int mf=0;mf<MF;mf++) af[mf] = ldfrag(&As[(wr + mf*16 + l15)*32 + l4*8]);
    #pragma unroll
    for (int nf=0;nf<NF;nf++) bfr[nf] = ldfrag(&Bs[(wc + nf*16 + l15)*32 + l4*8]);
    #pragma unroll
    for (int mf=0;mf<MF;mf++)
      #pragma unroll
      for (int nf=0;nf<NF;nf++)
        acc[mf][nf] = __builtin_amdgcn_mfma_f32_16x16x32_bf16(af[mf], bfr[nf], acc[mf][nf], 0, 0, 0);
    __syncthreads();
  }

  // epilogue: C/D layout col=lane&15, row=(lane>>4)*4+reg
  #pragma unroll
  for (int mf=0;mf<MF;mf++){
    #pragma unroll
    for (int nf=0;nf<NF;nf++){
      const int col = bn*BN + wc + nf*16 + l15;
      const float bv = bias[col];
      const int rowb = bm*BM + wr + mf*16 + l4*4;
      if (EPI == 0){
        #pragma unroll
        for (int r=0;r<4;r++)
          outF[(size_t)(rowb + r) * Nn + col] = acc[mf][nf][r] + bv;
      } else {
        const int s = col >> 9, hh = (col >> 6) & 7, d = col & 63;
        const int b = rowb >> 11, n = rowb & 2047;
        if (s == 2){
          // V transposed [B,H,D,N]: 4 consecutive n at fixed d -> one 8B write
          *(uint2*)&Vb[(((size_t)b*NH + hh)*ND + d)*NN + n] =
            make_uint2(pkbf2(acc[mf][nf][0]+bv, acc[mf][nf][1]+bv),
                       pkbf2(acc[mf][nf][2]+bv, acc[mf][nf][3]+bv));
        } else {
          unsigned short* dst = (s == 0) ? Qb : Kb;
          const float sc = (s == 0) ? ATT_SCALE : 1.f;
          #pragma unroll
          for (int r=0;r<4;r++)
            dst[(((size_t)b*NH + hh)*NN + (n + r))*ND + d] = f2bf((acc[mf][nf][r]+bv)*sc);
        }
      }
    }
  }
}

// Fused flash attention — r14 verified structure (unchanged): conv folded into
// Qt*log2e, swapped QK^T, 2 key-groups x 4 q-waves, sigma-permuted V slots +
// 4-shfl exchange, ones-MFMA row-sum, x2-unrolled loop with literal buffers,
// incremented staging pointers.
__global__ __launch_bounds__(512, 4) void attn_kernel(
    const unsigned short* __restrict__ Qb, const unsigned short* __restrict__ Kb,
    const unsigned short* __restrict__ Vb, const float* __restrict__ conv_w,
    const float* __restrict__ conv_b, unsigned short* __restrict__ AO)
{
  // [group][buf][64*64] u16 each for K and V; combine area aliases K after loop
  __shared__ __align__(16) char smem[65536];
  unsigned short* Klds = (unsigned short*)smem;            // 4 x 8KB
  unsigned short* Vlds = (unsigned short*)(smem + 32768);  // 4 x 8KB
  float* comb = (float*)smem;                              // 17.4KB used post-loop

  const int tid = threadIdx.x;
  const int w = tid >> 6, l = tid & 63;
  const int g = w >> 2, wq = w & 3;
  const int l4 = l >> 4, l15 = l & 15;
  const int qt = blockIdx.x, bh = blockIdx.y;
  const int h = bh & 7;
  const int q0 = qt * 64;
  const unsigned short* Qg = Qb + (size_t)bh * NN * ND;
  const unsigned short* Kg = Kb + (size_t)bh * NN * ND;
  const unsigned short* Vg = Vb + (size_t)bh * ND * NN;   // [D][N]
  float cw[5];
  #pragma unroll
  for (int o=0;o<5;o++) cw[o] = conv_w[h*5+o] * LOG2E;
  cw[2] += LOG2E;                              // (identity + center tap) * log2e
  // conv_b constant along key axis -> cancels in softmax.

  // ---- prologue: pre-convolved Qt (scaled by log2e) for this wave's 16 q ----
  bf16x8 qf[2];
  {
    const int q = q0 + wq*16 + l15;
    #pragma unroll
    for (int kc2=0;kc2<2;kc2++){
      float a8[8];
      #pragma unroll
      for (int j=0;j<8;j++) a8[j] = 0.f;
      #pragma unroll
      for (int o=0;o<5;o++){
        const int qg = q - 2 + o;
        if (qg >= 0 && qg < NN){
          u16x8 v = *(const u16x8*)(Qg + (size_t)qg*ND + kc2*32 + l4*8);
          #pragma unroll
          for (int j=0;j<8;j++) a8[j] = fmaf(cw[o], bf2f(v[j]), a8[j]);
        }
      }
      u16x8 pk;
      #pragma unroll
      for (int j=0;j<8;j++) pk[j] = f2bf(a8[j]);
      qf[kc2] = __builtin_bit_cast(bf16x8, pk);
    }
  }

  // staging geometry (r10-verified): group g's 4 waves stage K ([key][d]) and
  // V^T ([d][slot], sigma-permuted); source pre-swizzled -> linear LDS image
  // equals the XOR-swizzled layout.
  const int srow0 = wq*16 + (l>>3);
  const int scg   = (l&7) ^ (l>>3);
  const int soffK = scg * 8;
  const int soffV = ((scg & 4) | ((scg & 1) << 1) | ((scg >> 1) & 1)) * 8;  // sigma

  // incremented staging pointers (advance by constants; no per-iter rebuilds)
  const unsigned short* kgp = Kg + (size_t)(g*64 + srow0)*ND + soffK;
  const unsigned short* vgp = Vg + (size_t)srow0*NN + g*64 + soffV;
  // compile-time-selected LDS dests (literal buf in unrolled loop)
  unsigned short* kd0[2]; unsigned short* kd1[2];
  unsigned short* vd0[2]; unsigned short* vd1[2];
  #pragma unroll
  for (int b2=0;b2<2;b2++){
    kd0[b2] = &Klds[((g*2+b2)*64 + wq*16    )*64];
    kd1[b2] = &Klds[((g*2+b2)*64 + wq*16 + 8)*64];
    vd0[b2] = &Vlds[((g*2+b2)*64 + wq*16    )*64];
    vd1[b2] = &Vlds[((g*2+b2)*64 + wq*16 + 8)*64];
  }
  #define STAGE(BUF)                      \
    gload16(kgp,        kd0[BUF]);        \
    gload16(kgp + 8*ND, kd1[BUF]);        \
    gload16(vgp,        vd0[BUF]);        \
    gload16(vgp + 8*NN, vd1[BUF]);        \
    kgp += 128*ND; vgp += 128;

  STAGE(0)                                 // tile g into buf 0

  f32x4 oacc[4];
  #pragma unroll
  for (int i=0;i<4;i++)
    #pragma unroll
    for (int r=0;r<4;r++) oacc[i][r] = 0.f;
  f32x4 l_acc;                             // ones-MFMA row-sum accumulator
  #pragma unroll
  for (int r=0;r<4;r++) l_acc[r] = 0.f;

  u16x8 ones_u;
  #pragma unroll
  for (int j=0;j<8;j++) ones_u[j] = 0x3F80;   // bf16 1.0
  const bf16x8 ones = __builtin_bit_cast(bf16x8, ones_u);

  const int sz = (l15 & 7) << 4;           // frag-read XOR (row&7 = l15&7)
  const bool ue = (l4 & 1);

  __syncthreads();   // both groups' tile 0 staged & drained

  // one full iteration consuming buffer BUF (r10-verified body + ones-MFMA)
  #define COMPUTE(BUF)                                                          \
  {                                                                             \
    const char* kbp = (const char*)&Klds[(g*2+(BUF))*4096];                     \
    const char* vbp = (const char*)&Vlds[(g*2+(BUF))*4096];                     \
    f32x4 sacc[4];                                                              \
    __builtin_amdgcn_s_setprio(1);                                              \
    _Pragma("unroll")                                                           \
    for (int kf=0;kf<4;kf++){                                                   \
      const char* kb = kbp + (kf*16 + l15)*128;                                 \
      bf16x8 k0f = ldfrag(kb + ((l4*16)      ^ sz));                            \
      bf16x8 k1f = ldfrag(kb + ((64 + l4*16) ^ sz));                            \
      f32x4 s;                                                                  \
      _Pragma("unroll")                                                         \
      for (int r=0;r<4;r++) s[r] = 0.f;                                         \
      s = __builtin_amdgcn_mfma_f32_16x16x32_bf16(k0f, qf[0], s, 0,0,0);        \
      sacc[kf] = __builtin_amdgcn_mfma_f32_16x16x32_bf16(k1f, qf[1], s, 0,0,0); \
    }                                                                           \
    __builtin_amdgcn_s_setprio(0);                                              \
    bf16x8 vf[4][2];                                                            \
    _Pragma("unroll")                                                           \
    for (int df=0;df<4;df++){                                                   \
      const char* vb = vbp + (df*16 + l15)*128;                                 \
      vf[df][0] = ldfrag(vb + ((l4*16)      ^ sz));                             \
      vf[df][1] = ldfrag(vb + ((64 + l4*16) ^ sz));                             \
    }                                                                           \
    float p16[16];                                                              \
    _Pragma("unroll")                                                           \
    for (int kf=0;kf<4;kf++)                                                    \
      _Pragma("unroll")                                                         \
      for (int r=0;r<4;r++) p16[kf*4+r] = exp2_hw(sacc[kf][r]);                 \
    unsigned int pk8[8];                                                        \
    _Pragma("unroll")                                                           \
    for (int kf=0;kf<4;kf++)                                                    \
      _Pragma("unroll")                                                         \
      for (int j=0;j<2;j++)                                                     \
        pk8[2*kf+j] = cvtpk_bf2(p16[kf*4+2*j], p16[kf*4+2*j+1]);                \
    const unsigned int r1 = (unsigned int)__shfl_xor((int)(ue ? pk8[0] : pk8[2]), 16); \
    const unsigned int r2 = (unsigned int)__shfl_xor((int)(ue ? pk8[1] : pk8[3]), 16); \
    const unsigned int r3 = (unsigned int)__shfl_xor((int)(ue ? pk8[4] : pk8[6]), 16); \
    const unsigned int r4 = (unsigned int)__shfl_xor((int)(ue ? pk8[5] : pk8[7]), 16); \
    const uint4 b0u = ue ? make_uint4(r1, r2, pk8[2], pk8[3])                   \
                         : make_uint4(pk8[0], pk8[1], r1, r2);                  \
    const uint4 b1u = ue ? make_uint4(r3, r4, pk8[6], pk8[7])                   \
                         : make_uint4(pk8[4], pk8[5], r3, r4);                  \
    const bf16x8 pb0 = __builtin_bit_cast(bf16x8, b0u);                         \
    const bf16x8 pb1 = __builtin_bit_cast(bf16x8, b1u);                         \
    __builtin_amdgcn_s_setprio(1);                                              \
    l_acc = __builtin_amdgcn_mfma_f32_16x16x32_bf16(ones, pb0, l_acc, 0,0,0);   \
    l_acc = __builtin_amdgcn_mfma_f32_16x16x32_bf16(ones, pb1, l_acc, 0,0,0);   \
    _Pragma("unroll")                                                           \
    for (int df=0;df<4;df++){                                                   \
      oacc[df] = __builtin_amdgcn_mfma_f32_16x16x32_bf16(vf[df][0], pb0, oacc[df], 0,0,0); \
      oacc[df] = __builtin_amdgcn_mfma_f32_16x16x32_bf16(vf[df][1], pb1, oacc[df], 0,0,0); \
    }                                                                           \
    __builtin_amdgcn_s_setprio(0);                                              \
    __syncthreads();                                                            \
  }

  for (int i = 0; i < 8; ++i){
    STAGE(1)                 // tile 2*(2i)+2+g
    COMPUTE(0)               // it = 2i
    if (i < 7){ STAGE(0) }   // tile 2*(2i+1)+2+g
    COMPUTE(1)               // it = 2i+1
  }

  // ---- cross-group combine (linear partials), then normalize + store ----
  // l_acc[0] holds the full key-sum for q = wq*16 + l15 (all rows equal).
  if (g == 1){
    float* pb = comb + ((size_t)(wq*64 + l))*17;
    #pragma unroll
    for (int df=0;df<4;df++)
      #pragma unroll
      for (int r=0;r<4;r++) pb[df*4+r] = oacc[df][r];
    pb[16] = l_acc[0];
  }
  __syncthreads();
  if (g == 0){
    const float* pb = comb + ((size_t)(wq*64 + l))*17;
    #pragma unroll
    for (int df=0;df<4;df++)
      #pragma unroll
      for (int r=0;r<4;r++) oacc[df][r] += pb[df*4+r];
    const float l_tot = l_acc[0] + pb[16];

    const float inv = 1.f / l_tot;
    const int b = bh >> 3;
    const int q = q0 + wq*16 + l15;
    unsigned short* aoq = AO + ((size_t)(b*NN + q))*NC + h*64;
    #pragma unroll
    for (int df=0;df<4;df++)
      *(uint2*)(aoq + df*16 + l4*4) =
        make_uint2(pkbf2(oacc[df][0]*inv, oacc[df][1]*inv),
                   pkbf2(oacc[df][2]*inv, oacc[df][3]*inv));
  }
}

extern "C" void kernel_launch(void* const* d_in, const int* in_sizes, int n_in,
                              void* d_out, int out_size, void* d_ws, size_t ws_size,
                              hipStream_t stream)
{
  const float* x      = (const float*)d_in[0];
  const float* w_qkv  = (const float*)d_in[1];
  const float* b_qkv  = (const float*)d_in[2];
  const float* w_proj = (const float*)d_in[3];
  const float* b_proj = (const float*)d_in[4];
  const float* conv_w = (const float*)d_in[5];
  const float* conv_b = (const float*)d_in[6];
  float* out = (float*)d_out;

  char* ws = (char*)d_ws;                       // ~22 MB used
  unsigned short* wqkvb  = (unsigned short*)(ws + 4194304);
  unsigned short* wprojb = (unsigned short*)(ws + 5767168);
  unsigned short* Qb     = (unsigned short*)(ws + 6291456);
  unsigned short* Kb     = (unsigned short*)(ws + 10485760);
  unsigned short* Vb     = (unsigned short*)(ws + 14680064);  // [B,H,D,N]
  unsigned short* AO     = (unsigned short*)(ws + 18874368);

  // weights only (x is converted inline in GEMM1's A-staging)
  f2bf2_kernel<<<1024, 256, 0, stream>>>(w_qkv, wqkvb, NF3*NC,
                                         w_proj, wprojb, NC*NC);

  // BM=64,BN=128, AF32=1: A = x (f32) converted in-staging; grid 768 = 3/CU
  gemm_bt<1,64,128,1><<<dim3(64,12), 256, 0, stream>>>(x, wqkvb, b_qkv, nullptr,
                                                       Qb, Kb, Vb, NB*NN, NF3, NC);

  attn_kernel<<<dim3(32,16), 512, 0, stream>>>(Qb, Kb, Vb, conv_w, conv_b, AO);

  // BM=64,BN=64: grid (64,8) = 512 blocks = 2 blocks/CU exact
  gemm_bt<0,64,64,0><<<dim3(64,8), 256, 0, stream>>>(AO, wprojb, b_proj, out,
                                                     nullptr, nullptr, nullptr, NB*NN, NC, NC);
}

// Round 17
// 59.717 us; speedup vs baseline: 1.0675x; 1.0675x over previous
//
#include <hip/hip_runtime.h>
#include <hip/hip_bf16.h>
#include <cstdint>
#include <cstddef>

// Problem constants (B=2, N=2048, C=512, H=8, D=64, EPEG_K=5)
#define NB 2
#define NN 2048
#define NC 512
#define NH 8
#define ND 64
#define NF3 1536
#define ATT_SCALE 0.125f
#define LOG2E 1.44269504088896340736f

typedef __bf16 bf16x8 __attribute__((ext_vector_type(8)));
typedef unsigned short u16x8 __attribute__((ext_vector_type(8)));
typedef float f32x4 __attribute__((ext_vector_type(4)));

// round-to-nearest-even f32 -> bf16 (inputs are finite)
__device__ __forceinline__ unsigned short f2bf(float f){
  unsigned int u = __builtin_bit_cast(unsigned int, f);
  u += 0x7fffu + ((u >> 16) & 1u);
  return (unsigned short)(u >> 16);
}
__device__ __forceinline__ float bf2f(unsigned short s){
  unsigned int u = ((unsigned int)s) << 16;
  return __builtin_bit_cast(float, u);
}
// pack two f32 -> one u32 of 2 bf16 (RNE)
__device__ __forceinline__ unsigned int pkbf2(float lo, float hi){
  return (unsigned int)f2bf(lo) | ((unsigned int)f2bf(hi) << 16);
}
// hardware packed convert: dst = {bf16(lo), bf16(hi)} (RNE), 1 instruction
__device__ __forceinline__ unsigned int cvtpk_bf2(float lo, float hi){
  unsigned int r;
  asm("v_cvt_pk_bf16_f32 %0, %1, %2" : "=v"(r) : "v"(lo), "v"(hi));
  return r;
}
// hardware exp2: D = 2^S0 (v_exp_f32 IS the 2^x op)
__device__ __forceinline__ float exp2_hw(float x){
  float r;
  asm("v_exp_f32 %0, %1" : "=v"(r) : "v"(x));
  return r;
}

__device__ __forceinline__ bf16x8 ldfrag(const void* p){
  return __builtin_bit_cast(bf16x8, *(const u16x8*)p);
}

// async global->LDS, 16B per lane; LDS dest = wave-uniform base + lane*16,
// global source is PER-LANE (swizzled LDS layout = pre-swizzled source).
__device__ __forceinline__ void gload16(const void* g, void* l){
  __builtin_amdgcn_global_load_lds((const __attribute__((address_space(1))) unsigned int*)g,
                                   (__attribute__((address_space(3))) unsigned int*)l, 16, 0, 0);
}

// one kernel converts all three fp32 inputs to bf16 (chunks never straddle:
// all three sizes are multiples of 4)
__global__ void f2bf3_kernel(const float* __restrict__ a, unsigned short* __restrict__ oa, int na,
                             const float* __restrict__ b, unsigned short* __restrict__ ob, int nb,
                             const float* __restrict__ c, unsigned short* __restrict__ oc, int nc){
  int i = (blockIdx.x * 256 + threadIdx.x) * 4;
  const float* src; unsigned short* dst; int off;
  if (i < na)            { src = a; dst = oa; off = i; }
  else if (i < na + nb)  { src = b; dst = ob; off = i - na; }
  else if (i < na+nb+nc) { src = c; dst = oc; off = i - na - nb; }
  else return;
  float4 v = *(const float4*)(src + off);
  *(uint2*)(dst + off) = make_uint2(pkbf2(v.x, v.y), pkbf2(v.z, v.w));
}

// C = A[M,K] @ B[N,K]^T + bias.  A,B bf16 row-major (K contiguous), fp32 accum.
// BM x BN block tile, 4 waves, wave tile (BM/2)x(BN/2).
// KS = K-step per barrier interval: 32 (r15-verified, 64B rows, linear) or
// 64 (128B rows, attn-verified XOR swizzle: pre-swizzled gload source granule
// ((l&7)^(l>>3))*8, frag-read byte XOR (row&7)<<4 -> conflict-free).
// EPI==0: write fp32 to outF[M,Nn]. EPI==1: scatter bf16 Q/K/V (V transposed).
template<int EPI, int BM, int BN, int KS>
__global__ __launch_bounds__(256, (BM == 64 ? 3 : 2)) void gemm_bt(
    const unsigned short* __restrict__ A, const unsigned short* __restrict__ Bm,
    const float* __restrict__ bias, float* __restrict__ outF,
    unsigned short* __restrict__ Qb, unsigned short* __restrict__ Kb,
    unsigned short* __restrict__ Vb, int M, int Nn, int K)
{
  __shared__ unsigned short As[BM*KS];
  __shared__ unsigned short Bs[BN*KS];
  const int tid = threadIdx.x;
  const int w = tid >> 6, l = tid & 63;
  const int bm = blockIdx.x, bn = blockIdx.y;
  const int wr = (w >> 1) * (BM/2), wc = (w & 1) * (BN/2);
  const int l4 = l >> 4, l15 = l & 15;
  constexpr int MF = BM / 32;             // m-frags per wave
  constexpr int NF = BN / 32;             // n-frags per wave
  constexpr int KK = KS / 32;             // k-subfrags per tile

  f32x4 acc[MF][NF];
  #pragma unroll
  for (int i=0;i<MF;i++)
    #pragma unroll
    for (int j=0;j<NF;j++)
      #pragma unroll
      for (int r=0;r<4;r++) acc[i][j][r] = 0.f;

  const int szg = (l15 & 7) << 4;         // frag-read XOR for KS=64 path
  const int KT = K / KS;
  for (int kt = 0; kt < KT; ++kt){
    const int kc = kt * KS;
    if constexpr (KS == 32){
      #pragma unroll
      for (int c = 0; c < BM/64; ++c){    // A: 16-row chunks, 64B rows, linear
        const int rbase = w*(BM/4) + c*16;
        gload16(A + (size_t)(bm*BM + rbase + (l>>2))*K + kc + (l&3)*8, &As[rbase*32]);
      }
      #pragma unroll
      for (int c = 0; c < BN/64; ++c){
        const int rbase = w*(BN/4) + c*16;
        gload16(Bm + (size_t)(bn*BN + rbase + (l>>2))*K + kc + (l&3)*8, &Bs[rbase*32]);
      }
    } else {
      // KS=64: 8-row chunks, 128B rows, XOR-swizzled via pre-swizzled source
      const int srow = l >> 3;
      const int scol = ((l&7) ^ (l>>3)) * 8;
      #pragma unroll
      for (int c = 0; c < BM/32; ++c){
        const int r0 = w*(BM/4) + c*8;
        gload16(A + (size_t)(bm*BM + r0 + srow)*K + kc + scol, &As[r0*64]);
      }
      #pragma unroll
      for (int c = 0; c < BN/32; ++c){
        const int r0 = w*(BN/4) + c*8;
        gload16(Bm + (size_t)(bn*BN + r0 + srow)*K + kc + scol, &Bs[r0*64]);
      }
    }
    __syncthreads();
    bf16x8 af[MF][KK], bfr[NF][KK];
    #pragma unroll
    for (int mf=0;mf<MF;mf++)
      #pragma unroll
      for (int kk=0;kk<KK;kk++){
        if constexpr (KS == 32)
          af[mf][kk] = ldfrag(&As[(wr + mf*16 + l15)*32 + l4*8]);
        else
          af[mf][kk] = ldfrag((const char*)As + (wr + mf*16 + l15)*128 + ((kk*64 + l4*16) ^ szg));
      }
    #pragma unroll
    for (int nf=0;nf<NF;nf++)
      #pragma unroll
      for (int kk=0;kk<KK;kk++){
        if constexpr (KS == 32)
          bfr[nf][kk] = ldfrag(&Bs[(wc + nf*16 + l15)*32 + l4*8]);
        else
          bfr[nf][kk] = ldfrag((const char*)Bs + (wc + nf*16 + l15)*128 + ((kk*64 + l4*16) ^ szg));
      }
    #pragma unroll
    for (int mf=0;mf<MF;mf++)
      #pragma unroll
      for (int nf=0;nf<NF;nf++)
        #pragma unroll
        for (int kk=0;kk<KK;kk++)
          acc[mf][nf] = __builtin_amdgcn_mfma_f32_16x16x32_bf16(af[mf][kk], bfr[nf][kk], acc[mf][nf], 0, 0, 0);
    __syncthreads();
  }

  // epilogue: C/D layout col=lane&15, row=(lane>>4)*4+reg
  #pragma unroll
  for (int mf=0;mf<MF;mf++){
    #pragma unroll
    for (int nf=0;nf<NF;nf++){
      const int col = bn*BN + wc + nf*16 + l15;
      const float bv = bias[col];
      const int rowb = bm*BM + wr + mf*16 + l4*4;
      if (EPI == 0){
        #pragma unroll
        for (int r=0;r<4;r++)
          outF[(size_t)(rowb + r) * Nn + col] = acc[mf][nf][r] + bv;
      } else {
        const int s = col >> 9, hh = (col >> 6) & 7, d = col & 63;
        const int b = rowb >> 11, n = rowb & 2047;
        if (s == 2){
          // V transposed [B,H,D,N]: 4 consecutive n at fixed d -> one 8B write
          *(uint2*)&Vb[(((size_t)b*NH + hh)*ND + d)*NN + n] =
            make_uint2(pkbf2(acc[mf][nf][0]+bv, acc[mf][nf][1]+bv),
                       pkbf2(acc[mf][nf][2]+bv, acc[mf][nf][3]+bv));
        } else {
          unsigned short* dst = (s == 0) ? Qb : Kb;
          const float sc = (s == 0) ? ATT_SCALE : 1.f;
          #pragma unroll
          for (int r=0;r<4;r++)
            dst[(((size_t)b*NH + hh)*NN + (n + r))*ND + d] = f2bf((acc[mf][nf][r]+bv)*sc);
        }
      }
    }
  }
}

// Fused flash attention — r14 verified structure (unchanged): conv folded into
// Qt*log2e, swapped QK^T, 2 key-groups x 4 q-waves, sigma-permuted V slots +
// 4-shfl exchange, ones-MFMA row-sum, x2-unrolled loop with literal buffers,
// incremented staging pointers.
__global__ __launch_bounds__(512, 4) void attn_kernel(
    const unsigned short* __restrict__ Qb, const unsigned short* __restrict__ Kb,
    const unsigned short* __restrict__ Vb, const float* __restrict__ conv_w,
    const float* __restrict__ conv_b, unsigned short* __restrict__ AO)
{
  // [group][buf][64*64] u16 each for K and V; combine area aliases K after loop
  __shared__ __align__(16) char smem[65536];
  unsigned short* Klds = (unsigned short*)smem;            // 4 x 8KB
  unsigned short* Vlds = (unsigned short*)(smem + 32768);  // 4 x 8KB
  float* comb = (float*)smem;                              // 17.4KB used post-loop

  const int tid = threadIdx.x;
  const int w = tid >> 6, l = tid & 63;
  const int g = w >> 2, wq = w & 3;
  const int l4 = l >> 4, l15 = l & 15;
  const int qt = blockIdx.x, bh = blockIdx.y;
  const int h = bh & 7;
  const int q0 = qt * 64;
  const unsigned short* Qg = Qb + (size_t)bh * NN * ND;
  const unsigned short* Kg = Kb + (size_t)bh * NN * ND;
  const unsigned short* Vg = Vb + (size_t)bh * ND * NN;   // [D][N]
  float cw[5];
  #pragma unroll
  for (int o=0;o<5;o++) cw[o] = conv_w[h*5+o] * LOG2E;
  cw[2] += LOG2E;                              // (identity + center tap) * log2e
  // conv_b constant along key axis -> cancels in softmax.

  // ---- prologue: pre-convolved Qt (scaled by log2e) for this wave's 16 q ----
  bf16x8 qf[2];
  {
    const int q = q0 + wq*16 + l15;
    #pragma unroll
    for (int kc2=0;kc2<2;kc2++){
      float a8[8];
      #pragma unroll
      for (int j=0;j<8;j++) a8[j] = 0.f;
      #pragma unroll
      for (int o=0;o<5;o++){
        const int qg = q - 2 + o;
        if (qg >= 0 && qg < NN){
          u16x8 v = *(const u16x8*)(Qg + (size_t)qg*ND + kc2*32 + l4*8);
          #pragma unroll
          for (int j=0;j<8;j++) a8[j] = fmaf(cw[o], bf2f(v[j]), a8[j]);
        }
      }
      u16x8 pk;
      #pragma unroll
      for (int j=0;j<8;j++) pk[j] = f2bf(a8[j]);
      qf[kc2] = __builtin_bit_cast(bf16x8, pk);
    }
  }

  // staging geometry (r10-verified): group g's 4 waves stage K ([key][d]) and
  // V^T ([d][slot], sigma-permuted); source pre-swizzled -> linear LDS image
  // equals the XOR-swizzled layout.
  const int srow0 = wq*16 + (l>>3);
  const int scg   = (l&7) ^ (l>>3);
  const int soffK = scg * 8;
  const int soffV = ((scg & 4) | ((scg & 1) << 1) | ((scg >> 1) & 1)) * 8;  // sigma

  // incremented staging pointers (advance by constants; no per-iter rebuilds)
  const unsigned short* kgp = Kg + (size_t)(g*64 + srow0)*ND + soffK;
  const unsigned short* vgp = Vg + (size_t)srow0*NN + g*64 + soffV;
  // compile-time-selected LDS dests (literal buf in unrolled loop)
  unsigned short* kd0[2]; unsigned short* kd1[2];
  unsigned short* vd0[2]; unsigned short* vd1[2];
  #pragma unroll
  for (int b2=0;b2<2;b2++){
    kd0[b2] = &Klds[((g*2+b2)*64 + wq*16    )*64];
    kd1[b2] = &Klds[((g*2+b2)*64 + wq*16 + 8)*64];
    vd0[b2] = &Vlds[((g*2+b2)*64 + wq*16    )*64];
    vd1[b2] = &Vlds[((g*2+b2)*64 + wq*16 + 8)*64];
  }
  #define STAGE(BUF)                      \
    gload16(kgp,        kd0[BUF]);        \
    gload16(kgp + 8*ND, kd1[BUF]);        \
    gload16(vgp,        vd0[BUF]);        \
    gload16(vgp + 8*NN, vd1[BUF]);        \
    kgp += 128*ND; vgp += 128;

  STAGE(0)                                 // tile g into buf 0

  f32x4 oacc[4];
  #pragma unroll
  for (int i=0;i<4;i++)
    #pragma unroll
    for (int r=0;r<4;r++) oacc[i][r] = 0.f;
  f32x4 l_acc;                             // ones-MFMA row-sum accumulator
  #pragma unroll
  for (int r=0;r<4;r++) l_acc[r] = 0.f;

  u16x8 ones_u;
  #pragma unroll
  for (int j=0;j<8;j++) ones_u[j] = 0x3F80;   // bf16 1.0
  const bf16x8 ones = __builtin_bit_cast(bf16x8, ones_u);

  const int sz = (l15 & 7) << 4;           // frag-read XOR (row&7 = l15&7)
  const bool ue = (l4 & 1);

  __syncthreads();   // both groups' tile 0 staged & drained

  // one full iteration consuming buffer BUF (r10-verified body + ones-MFMA)
  #define COMPUTE(BUF)                                                          \
  {                                                                             \
    const char* kbp = (const char*)&Klds[(g*2+(BUF))*4096];                     \
    const char* vbp = (const char*)&Vlds[(g*2+(BUF))*4096];                     \
    f32x4 sacc[4];                                                              \
    __builtin_amdgcn_s_setprio(1);                                              \
    _Pragma("unroll")                                                           \
    for (int kf=0;kf<4;kf++){                                                   \
      const char* kb = kbp + (kf*16 + l15)*128;                                 \
      bf16x8 k0f = ldfrag(kb + ((l4*16)      ^ sz));                            \
      bf16x8 k1f = ldfrag(kb + ((64 + l4*16) ^ sz));                            \
      f32x4 s;                                                                  \
      _Pragma("unroll")                                                         \
      for (int r=0;r<4;r++) s[r] = 0.f;                                         \
      s = __builtin_amdgcn_mfma_f32_16x16x32_bf16(k0f, qf[0], s, 0,0,0);        \
      sacc[kf] = __builtin_amdgcn_mfma_f32_16x16x32_bf16(k1f, qf[1], s, 0,0,0); \
    }                                                                           \
    __builtin_amdgcn_s_setprio(0);                                              \
    bf16x8 vf[4][2];                                                            \
    _Pragma("unroll")                                                           \
    for (int df=0;df<4;df++){                                                   \
      const char* vb = vbp + (df*16 + l15)*128;                                 \
      vf[df][0] = ldfrag(vb + ((l4*16)      ^ sz));                             \
      vf[df][1] = ldfrag(vb + ((64 + l4*16) ^ sz));                             \
    }                                                                           \
    float p16[16];                                                              \
    _Pragma("unroll")                                                           \
    for (int kf=0;kf<4;kf++)                                                    \
      _Pragma("unroll")                                                         \
      for (int r=0;r<4;r++) p16[kf*4+r] = exp2_hw(sacc[kf][r]);                 \
    unsigned int pk8[8];                                                        \
    _Pragma("unroll")                                                           \
    for (int kf=0;kf<4;kf++)                                                    \
      _Pragma("unroll")                                                         \
      for (int j=0;j<2;j++)                                                     \
        pk8[2*kf+j] = cvtpk_bf2(p16[kf*4+2*j], p16[kf*4+2*j+1]);                \
    const unsigned int r1 = (unsigned int)__shfl_xor((int)(ue ? pk8[0] : pk8[2]), 16); \
    const unsigned int r2 = (unsigned int)__shfl_xor((int)(ue ? pk8[1] : pk8[3]), 16); \
    const unsigned int r3 = (unsigned int)__shfl_xor((int)(ue ? pk8[4] : pk8[6]), 16); \
    const unsigned int r4 = (unsigned int)__shfl_xor((int)(ue ? pk8[5] : pk8[7]), 16); \
    const uint4 b0u = ue ? make_uint4(r1, r2, pk8[2], pk8[3])                   \
                         : make_uint4(pk8[0], pk8[1], r1, r2);                  \
    const uint4 b1u = ue ? make_uint4(r3, r4, pk8[6], pk8[7])                   \
                         : make_uint4(pk8[4], pk8[5], r3, r4);                  \
    const bf16x8 pb0 = __builtin_bit_cast(bf16x8, b0u);                         \
    const bf16x8 pb1 = __builtin_bit_cast(bf16x8, b1u);                         \
    __builtin_amdgcn_s_setprio(1);                                              \
    l_acc = __builtin_amdgcn_mfma_f32_16x16x32_bf16(ones, pb0, l_acc, 0,0,0);   \
    l_acc = __builtin_amdgcn_mfma_f32_16x16x32_bf16(ones, pb1, l_acc, 0,0,0);   \
    _Pragma("unroll")                                                           \
    for (int df=0;df<4;df++){                                                   \
      oacc[df] = __builtin_amdgcn_mfma_f32_16x16x32_bf16(vf[df][0], pb0, oacc[df], 0,0,0); \
      oacc[df] = __builtin_amdgcn_mfma_f32_16x16x32_bf16(vf[df][1], pb1, oacc[df], 0,0,0); \
    }                                                                           \
    __builtin_amdgcn_s_setprio(0);                                              \
    __syncthreads();                                                            \
  }

  for (int i = 0; i < 8; ++i){
    STAGE(1)                 // tile 2*(2i)+2+g
    COMPUTE(0)               // it = 2i
    if (i < 7){ STAGE(0) }   // tile 2*(2i+1)+2+g
    COMPUTE(1)               // it = 2i+1
  }

  // ---- cross-group combine (linear partials), then normalize + store ----
  // l_acc[0] holds the full key-sum for q = wq*16 + l15 (all rows equal).
  if (g == 1){
    float* pb = comb + ((size_t)(wq*64 + l))*17;
    #pragma unroll
    for (int df=0;df<4;df++)
      #pragma unroll
      for (int r=0;r<4;r++) pb[df*4+r] = oacc[df][r];
    pb[16] = l_acc[0];
  }
  __syncthreads();
  if (g == 0){
    const float* pb = comb + ((size_t)(wq*64 + l))*17;
    #pragma unroll
    for (int df=0;df<4;df++)
      #pragma unroll
      for (int r=0;r<4;r++) oacc[df][r] += pb[df*4+r];
    const float l_tot = l_acc[0] + pb[16];

    const float inv = 1.f / l_tot;
    const int b = bh >> 3;
    const int q = q0 + wq*16 + l15;
    unsigned short* aoq = AO + ((size_t)(b*NN + q))*NC + h*64;
    #pragma unroll
    for (int df=0;df<4;df++)
      *(uint2*)(aoq + df*16 + l4*4) =
        make_uint2(pkbf2(oacc[df][0]*inv, oacc[df][1]*inv),
                   pkbf2(oacc[df][2]*inv, oacc[df][3]*inv));
  }
}

extern "C" void kernel_launch(void* const* d_in, const int* in_sizes, int n_in,
                              void* d_out, int out_size, void* d_ws, size_t ws_size,
                              hipStream_t stream)
{
  const float* x      = (const float*)d_in[0];
  const float* w_qkv  = (const float*)d_in[1];
  const float* b_qkv  = (const float*)d_in[2];
  const float* w_proj = (const float*)d_in[3];
  const float* b_proj = (const float*)d_in[4];
  const float* conv_w = (const float*)d_in[5];
  const float* conv_b = (const float*)d_in[6];
  float* out = (float*)d_out;

  char* ws = (char*)d_ws;                       // ~22 MB used
  unsigned short* xb     = (unsigned short*)(ws);
  unsigned short* wqkvb  = (unsigned short*)(ws + 4194304);
  unsigned short* wprojb = (unsigned short*)(ws + 5767168);
  unsigned short* Qb     = (unsigned short*)(ws + 6291456);
  unsigned short* Kb     = (unsigned short*)(ws + 10485760);
  unsigned short* Vb     = (unsigned short*)(ws + 14680064);  // [B,H,D,N]
  unsigned short* AO     = (unsigned short*)(ws + 18874368);

  f2bf3_kernel<<<3072, 256, 0, stream>>>(x, xb, NB*NN*NC,
                                         w_qkv, wqkvb, NF3*NC,
                                         w_proj, wprojb, NC*NC);

  // BM=64,BN=128,KS=64: grid 768 = 3/CU exact; 8 barrier drains (was 16),
  // attn-pattern swizzle -> conflict-free 128B-row frag reads
  gemm_bt<1,64,128,64><<<dim3(64,12), 256, 0, stream>>>(xb, wqkvb, b_qkv, nullptr,
                                                        Qb, Kb, Vb, NB*NN, NF3, NC);

  attn_kernel<<<dim3(32,16), 512, 0, stream>>>(Qb, Kb, Vb, conv_w, conv_b, AO);

  // BM=64,BN=64,KS=32: grid (64,8) = 512 blocks = 2 blocks/CU (r15-verified)
  gemm_bt<0,64,64,32><<<dim3(64,8), 256, 0, stream>>>(AO, wprojb, b_proj, out,
                                                      nullptr, nullptr, nullptr, NB*NN, NC, NC);
}